// Round 7
// baseline (7613.037 us; speedup 1.0000x reference)
//
#include <hip/hip_runtime.h>
#include <stdint.h>

// ---------------------------------------------------------------------------
// AWD-LSTM eval forward.  T=256, B=256, H=1024, FEAT=319 (=300+7+12), C=13.
// Layer1's recurrent carry is ignored by the reference -> only layer0 is
// sequential; layer1+decoder are parallel over rows.
// Round 7: persistent-chunk layer0 v2.  Rounds 3/5/6 all = 6.6 ms despite
// different k_step internals => per-launch fixed cost (~13 us) dominates.
// k_l0chunk runs CH steps in ONE kernel.  vs round-4's failed attempt:
//  - NO fences: h(t) goes to a FRESH slot per step (no stale-hit possible)
//    via agent-scope relaxed atomic u32 stores (write-through to L3);
//    readers use plain global_load_lds (cold address -> L3 -> fresh).
//  - 4-buffer vmcnt(4) staging pipeline (3 K-tiles in flight), R6-proven.
//  - W panels L2-resident across steps (XCD swizzle + no kernel boundaries).
//  - barrier: relaxed atomics only, 8 group counters + master, s_sleep poll.
// GEMMs: bf16 MFMA 16x16x32, f32 accum; weights gate-interleaved
// (col 4j+p = gate p of unit j) so the LSTM cell fuses into the epilogue.
// ---------------------------------------------------------------------------

typedef __attribute__((ext_vector_type(8))) short bf16x8;
typedef __attribute__((ext_vector_type(4))) float f32x4;

#define SLOT 262144ull  // 256*1024 elements per (B,H) slab

__device__ __forceinline__ uint16_t f2bf(float f) {
  uint32_t u = __float_as_uint(f);
  u += 0x7fffu + ((u >> 16) & 1u);
  return (uint16_t)(u >> 16);
}
__device__ __forceinline__ float bf2f(uint16_t h) {
  return __uint_as_float(((uint32_t)h) << 16);
}
__device__ __forceinline__ float sigmoidf_(float x) {
  return __builtin_amdgcn_rcpf(1.0f + __expf(-x));
}
__device__ __forceinline__ float tanhf_(float x) {
  return 1.0f - 2.0f * __builtin_amdgcn_rcpf(__expf(2.0f * x) + 1.0f);
}
__device__ __forceinline__ void gload_lds16(const void* g, void* l) {
  __builtin_amdgcn_global_load_lds(
      (const __attribute__((address_space(1))) void*)g,
      (__attribute__((address_space(3))) void*)l, 16, 0, 0);
}
// LDS tile: row-major [rows][32 k] bf16; four 16B chunks of each row stored
// permuted: chunk_pos = chunk ^ ((row>>1)&3)  -> ~2-way banks (free)
__device__ __forceinline__ bf16x8 lds_frag(const uint16_t* base, int row, int kc) {
  const uint16_t* p = base + row * 32 + ((kc ^ ((row >> 1) & 3)) << 3);
  return *(const bf16x8*)p;
}
__device__ __forceinline__ f32x4 mfma16(bf16x8 a, bf16x8 b, f32x4 c) {
  return __builtin_amdgcn_mfma_f32_16x16x32_bf16(a, b, c, 0, 0, 0);
}

// ---------------- weight prep ----------------
__global__ __launch_bounds__(256) void k_prep_w0(
    const float* __restrict__ wi0, const float* __restrict__ bi0,
    const float* __restrict__ wh0, const float* __restrict__ bh0,
    uint16_t* __restrict__ W0c, float* __restrict__ b0) {
  int r = blockIdx.x;            // interleaved output row: unit j, gate p
  int p = r & 3, j = r >> 2;
  int src = p * 1024 + j;
  const float* wi = wi0 + (size_t)src * 319;
  const float* wh = wh0 + (size_t)src * 1024;
  uint16_t* dst = W0c + (size_t)r * 1344;
  for (int k = threadIdx.x; k < 1344; k += 256) {
    float v;
    if (k < 319) v = wi[k];
    else if (k == 319) v = 0.0f;
    else v = wh[k - 320];
    dst[k] = f2bf(v);
  }
  if (threadIdx.x == 0) b0[r] = bi0[src] + bh0[src];
}

__global__ __launch_bounds__(256) void k_prep_w1(
    const float* __restrict__ wi1, const float* __restrict__ bi1,
    const float* __restrict__ wh1, const float* __restrict__ bh1,
    uint16_t* __restrict__ W1c, float* __restrict__ b1) {
  int r = blockIdx.x;
  int p = r & 3, j = r >> 2;
  int src = p * 1024 + j;
  const float* wi = wi1 + (size_t)src * 1024;
  const float* wh = wh1 + (size_t)src * 1024;
  uint16_t* dst = W1c + (size_t)r * 2048;
  for (int k = threadIdx.x; k < 2048; k += 256) {
    float v = (k < 1024) ? wi[k] : wh[k - 1024];
    dst[k] = f2bf(v);
  }
  if (threadIdx.x == 0) b1[r] = bi1[src] + bh1[src];
}

__global__ __launch_bounds__(256) void k_init(
    const float* __restrict__ h_init, const float* __restrict__ c_init,
    uint16_t* __restrict__ h_slot, float* __restrict__ c_state,
    uint32_t* __restrict__ bar) {
  int i = blockIdx.x * 256 + threadIdx.x;  // 262144 = 256*1024
  h_slot[i] = f2bf(h_init[i]);             // layer0 slice of h_init
  c_state[i] = c_init[i];
  if (i < 4096) bar[i] = 0;                // 256 steps x 16 u32
}

// ---------------- embedding + concat -> x_bf ----------------
__global__ __launch_bounds__(256) void k_embed(
    const int* __restrict__ tokens, const float* __restrict__ casing,
    const float* __restrict__ pos, const float* __restrict__ emb,
    uint16_t* __restrict__ x_bf) {
  int row = blockIdx.x * 4 + (threadIdx.x >> 6);  // (t*256+b)
  int l = threadIdx.x & 63;
  int tok = tokens[row];
  const float* er = emb + (size_t)tok * 300;
  uint16_t* xr = x_bf + (size_t)row * 320;
#pragma unroll
  for (int c0 = 0; c0 < 320; c0 += 64) {
    int c = c0 + l;
    float v;
    if (c < 300) v = er[c];
    else if (c < 307) v = casing[(size_t)row * 7 + (c - 300)];
    else if (c < 319) v = pos[(size_t)row * 12 + (c - 307)];
    else v = 0.0f;
    xr[c] = f2bf(v);
  }
}

// ---------------- persistent layer0 chunk (CH steps, 1 launch) ----------------
// 256 blocks (1/CU, all resident).  Block = (Mb batch-tile 64, Nb col-tile 64),
// XCD-chunked swizzle: XCD k owns col-panels [8k,8k+8) x 4 batch tiles ->
// W panel (172 KB/block, 1.4 MB/XCD) stays L2-resident across all steps.
// h slot per step is FRESH (never read/written before in this launch) ->
// plain loads are stale-proof; stores are agent-scope atomics (-> L3).
__global__ __launch_bounds__(256) void k_l0chunk(
    const uint16_t* __restrict__ x_bf, const uint16_t* __restrict__ W0c,
    const float* __restrict__ b0, uint16_t* __restrict__ h0buf,
    uint16_t* __restrict__ c0buf, float* __restrict__ c_st,
    uint32_t* __restrict__ bar, int t0, int CH, int in_s0) {
  __shared__ __align__(16) uint16_t As[4][2048];
  __shared__ __align__(16) uint16_t Bs[4][2048];
  __shared__ __align__(16) float epi[4][16][40];
  const int tid = threadIdx.x;
  const int w = tid >> 6, l = tid & 63;
  const int wr = w >> 1, wc = w & 1;
  const int lid = (blockIdx.x & 7) * 32 + (blockIdx.x >> 3);  // bijective
  const int Mb = (lid & 3) * 64;    // batch tile
  const int Nb = (lid >> 2) * 64;   // col tile (gate-interleaved)

  // staging geometry (R6-proven)
  const int srow = w * 16 + (l >> 2);
  const int sc = (l & 3) ^ ((l >> 3) & 3);
  const uint16_t* wrow = W0c + (size_t)(Nb + srow) * 1344 + sc * 8;

  // per-thread cell state: 4 fixed (bg, jg) cells across all steps
  const int jbase = (Nb + wc * 32) >> 2;
  float creg[4];
  int gidx4[4];
#pragma unroll
  for (int m = 0; m < 2; ++m)
#pragma unroll
    for (int it = 0; it < 2; ++it) {
      int pp = it * 64 + l;
      int bg = Mb + wr * 32 + m * 16 + (pp >> 3);
      int jg = jbase + (pp & 7);
      int ci = m * 2 + it;
      gidx4[ci] = bg * 1024 + jg;
      creg[ci] = c_st[gidx4[ci]];
    }

  for (int tl = 0; tl < CH; ++tl) {
    const int t = t0 + tl;
    const int is = (tl > 0) ? (tl - 1) : in_s0;
    const uint16_t* xrow =
        x_bf + ((size_t)t * 256 + Mb + srow) * 320 + sc * 8;
    const uint16_t* hrow =
        h0buf + (size_t)is * SLOT + (size_t)(Mb + srow) * 1024 + sc * 8;
    auto stage = [&](int kt, int buf) {
      int kg = kt * 32;
      const uint16_t* sA = (kt < 10) ? (xrow + kg) : (hrow + (kg - 320));
      gload_lds16(sA, &As[buf][w * 512]);
      gload_lds16(wrow + kg, &Bs[buf][w * 512]);
    };

    f32x4 acc[2][2] = {};
    stage(0, 0);
    stage(1, 1);
    stage(2, 2);
    for (int kt = 0; kt < 42; ++kt) {
      __builtin_amdgcn_sched_barrier(0);
      if (kt < 40) asm volatile("s_waitcnt vmcnt(4)" ::: "memory");
      else if (kt == 40) asm volatile("s_waitcnt vmcnt(2)" ::: "memory");
      else asm volatile("s_waitcnt vmcnt(0)" ::: "memory");
      __builtin_amdgcn_s_barrier();
      __builtin_amdgcn_sched_barrier(0);
      if (kt < 39) stage(kt + 3, (kt + 3) & 3);
      const uint16_t* Ab = As[kt & 3];
      const uint16_t* Bb = Bs[kt & 3];
      bf16x8 a0 = lds_frag(Ab, wr * 32 + (l & 15), l >> 4);
      bf16x8 a1 = lds_frag(Ab, wr * 32 + 16 + (l & 15), l >> 4);
      bf16x8 q0 = lds_frag(Bb, wc * 32 + (l & 15), l >> 4);
      bf16x8 q1 = lds_frag(Bb, wc * 32 + 16 + (l & 15), l >> 4);
      acc[0][0] = mfma16(a0, q0, acc[0][0]);
      acc[0][1] = mfma16(a0, q1, acc[0][1]);
      acc[1][0] = mfma16(a1, q0, acc[1][0]);
      acc[1][1] = mfma16(a1, q1, acc[1][1]);
    }

    // fused cell epilogue; h -> fresh slot tl via agent atomic u32 (pairs)
    uint32_t* hc = (uint32_t*)(h0buf + (size_t)tl * SLOT);
    uint32_t* cc = (uint32_t*)(c0buf + (size_t)tl * SLOT);
#pragma unroll
    for (int m = 0; m < 2; ++m) {
#pragma unroll
      for (int n = 0; n < 2; ++n)
#pragma unroll
        for (int r = 0; r < 4; ++r)
          epi[w][(l >> 4) * 4 + r][n * 16 + (l & 15)] = acc[m][n][r];
      asm volatile("s_waitcnt lgkmcnt(0)" ::: "memory");
#pragma unroll
      for (int it = 0; it < 2; ++it) {
        int pp = it * 64 + l;
        int rr = pp >> 3, j = pp & 7;
        f32x4 q = *(const f32x4*)&epi[w][rr][j * 4];
        f32x4 bv = *(const f32x4*)&b0[(jbase + j) * 4];
        float vi = sigmoidf_(q[0] + bv[0]);
        float vf = sigmoidf_(q[1] + bv[1]);
        float vo = sigmoidf_(q[2] + bv[2]);
        float vg = tanhf_(q[3] + bv[3]);
        int ci = m * 2 + it;
        float cn = vf * creg[ci] + vi * vg;
        creg[ci] = cn;
        float hh = vo * tanhf_(cn);
        uint32_t hu = f2bf(hh), cu = f2bf(cn);
        uint32_t hp = hu | ((uint32_t)__shfl_xor((int)hu, 1) << 16);
        uint32_t cp = cu | ((uint32_t)__shfl_xor((int)cu, 1) << 16);
        if ((l & 1) == 0) {
          size_t pidx = (size_t)(gidx4[ci] >> 1);
          __hip_atomic_store(hc + pidx, hp, __ATOMIC_RELAXED,
                             __HIP_MEMORY_SCOPE_AGENT);
          cc[pidx] = cp;
        }
      }
      asm volatile("s_waitcnt lgkmcnt(0)" ::: "memory");
    }

    // inter-step grid barrier (relaxed atomics; data already published via
    // sc-stores; __syncthreads drains vmcnt before the arrive)
    if (tl + 1 < CH) {
      __syncthreads();
      if (tid == 0) {
        uint32_t* bs = bar + (size_t)t * 16;
        uint32_t old = __hip_atomic_fetch_add(
            &bs[blockIdx.x & 7], 1u, __ATOMIC_RELAXED,
            __HIP_MEMORY_SCOPE_AGENT);
        if (old == 31u)
          __hip_atomic_fetch_add(&bs[8], 1u, __ATOMIC_RELAXED,
                                 __HIP_MEMORY_SCOPE_AGENT);
        int spins = 0;
        while (__hip_atomic_load(&bs[8], __ATOMIC_RELAXED,
                                 __HIP_MEMORY_SCOPE_AGENT) < 8u) {
          __builtin_amdgcn_s_sleep(1);
          if (++spins > 2000000) break;  // bounded: bug -> wrong, not hung
        }
      }
      __syncthreads();
      __builtin_amdgcn_sched_barrier(0);
    }
  }
#pragma unroll
  for (int ci = 0; ci < 4; ++ci) c_st[gidx4[ci]] = creg[ci];
}

// ---------------- layer1 GEMM over one chunk ----------------
// rows = CH*256; A row (t,b) = [h0(t,b) | h0(t,255-b)]  (slot tl of h0buf).
// tile 128x128, 4 waves (2x2) x (4x4 frags), fused cell epilogue.
// 1-D grid 64*CH, XCD-chunked swizzle: XCD k owns N-panels [4k,4k+4).
__global__ __launch_bounds__(256) void k_l1gemm(
    const uint16_t* __restrict__ h0buf, const uint16_t* __restrict__ W1c,
    const float* __restrict__ b1, const uint16_t* __restrict__ c0buf,
    uint16_t* __restrict__ h1buf) {
  __shared__ __align__(16) uint16_t As[128 * 32];
  __shared__ __align__(16) uint16_t Bs[128 * 32];
  __shared__ __align__(16) float epi[4][16][68];
  int tid = threadIdx.x;
  int w = tid >> 6, l = tid & 63;
  int wr = w >> 1, wc = w & 1;
  uint32_t G = gridDim.x;          // 64*CH (divisible by 8)
  uint32_t cpx = G >> 3;
  uint32_t lid = (blockIdx.x & 7) * cpx + (blockIdx.x >> 3);  // bijective
  uint32_t yyTot = G >> 5;         // 2*CH row-tiles per N-panel
  uint32_t nb = lid / yyTot;       // N-panel 0..31
  uint32_t yy = lid - nb * yyTot;  // row tile 0..2CH-1
  int Nb = (int)nb * 128;
  int tl = (int)(yy >> 1);
  int bbase = (int)(yy & 1) * 128;
  const uint16_t* hrow = h0buf + (size_t)tl * SLOT;
  const uint16_t* c0s = c0buf + (size_t)tl * SLOT;
  uint16_t* h1s = h1buf + (size_t)tl * SLOT;
  f32x4 acc[4][4] = {};

  int sc = (l & 3) ^ ((l >> 3) & 3);
  int srow0 = (w * 2 + 0) * 16 + (l >> 2);
  int srow1 = (w * 2 + 1) * 16 + (l >> 2);
  const uint16_t* hA0n = hrow + (size_t)(bbase + srow0) * 1024;
  const uint16_t* hA0f = hrow + (size_t)(255 - (bbase + srow0)) * 1024;
  const uint16_t* hA1n = hrow + (size_t)(bbase + srow1) * 1024;
  const uint16_t* hA1f = hrow + (size_t)(255 - (bbase + srow1)) * 1024;
  const uint16_t* wB0 = W1c + (size_t)(Nb + srow0) * 2048;
  const uint16_t* wB1 = W1c + (size_t)(Nb + srow1) * 2048;
  uint16_t* AsW0 = As + (w * 2 + 0) * 512;
  uint16_t* AsW1 = As + (w * 2 + 1) * 512;
  uint16_t* BsW0 = Bs + (w * 2 + 0) * 512;
  uint16_t* BsW1 = Bs + (w * 2 + 1) * 512;

  for (int kt = 0; kt < 64; ++kt) {
    int kg = kt * 32 + sc * 8;
    const uint16_t* sA0 = (kg < 1024) ? (hA0n + kg) : (hA0f + (kg - 1024));
    const uint16_t* sA1 = (kg < 1024) ? (hA1n + kg) : (hA1f + (kg - 1024));
    gload_lds16(sA0, AsW0);
    gload_lds16(sA1, AsW1);
    gload_lds16(wB0 + kg, BsW0);
    gload_lds16(wB1 + kg, BsW1);
    __syncthreads();
    bf16x8 a[4], q[4];
#pragma unroll
    for (int m = 0; m < 4; ++m) a[m] = lds_frag(As, wr * 64 + m * 16 + (l & 15), l >> 4);
#pragma unroll
    for (int n = 0; n < 4; ++n) q[n] = lds_frag(Bs, wc * 64 + n * 16 + (l & 15), l >> 4);
#pragma unroll
    for (int m = 0; m < 4; ++m)
#pragma unroll
      for (int n = 0; n < 4; ++n) acc[m][n] = mfma16(a[m], q[n], acc[m][n]);
    __syncthreads();
  }

  int jbase = (Nb + wc * 64) >> 2;
#pragma unroll
  for (int m = 0; m < 4; ++m) {
#pragma unroll
    for (int n = 0; n < 4; ++n)
#pragma unroll
      for (int r = 0; r < 4; ++r)
        epi[w][(l >> 4) * 4 + r][n * 16 + (l & 15)] = acc[m][n][r];
    asm volatile("s_waitcnt lgkmcnt(0)" ::: "memory");
#pragma unroll
    for (int it = 0; it < 4; ++it) {
      int pp = it * 64 + l;
      int rr = pp >> 4, j = pp & 15;
      f32x4 q = *(const f32x4*)&epi[w][rr][j * 4];
      f32x4 bv = *(const f32x4*)&b1[(size_t)(jbase + j) * 4];
      float vi = sigmoidf_(q[0] + bv[0]);
      float vf = sigmoidf_(q[1] + bv[1]);
      float vo = sigmoidf_(q[2] + bv[2]);
      float vg = tanhf_(q[3] + bv[3]);
      int rowl = wr * 64 + m * 16 + rr;
      int b = bbase + rowl;
      int jg = jbase + j;
      float c0v = bf2f(c0s[(size_t)(255 - b) * 1024 + jg]);
      float cn = vf * c0v + vi * vg;
      float hh = vo * tanhf_(cn);
      h1s[(size_t)b * 1024 + jg] = f2bf(hh);
    }
    asm volatile("s_waitcnt lgkmcnt(0)" ::: "memory");
  }
}

// ---------------- decoder over one chunk ----------------
__global__ __launch_bounds__(256) void k_decode(
    const uint16_t* __restrict__ h0buf, const uint16_t* __restrict__ h1buf,
    const float* __restrict__ dec_w, const float* __restrict__ dec_b,
    float* __restrict__ out, int t0) {
  int rowl = blockIdx.x * 4 + (threadIdx.x >> 6);  // chunk-local row
  int l = threadIdx.x & 63;
  int tl = rowl >> 8, b = rowl & 255;
  const uint16_t* h0 = h0buf + (size_t)tl * SLOT + (size_t)b * 1024;
  const uint16_t* h1 = h1buf + (size_t)tl * SLOT + (size_t)b * 1024;
  float acc[13];
#pragma unroll
  for (int c = 0; c < 13; ++c) acc[c] = 0.0f;
#pragma unroll
  for (int part = 0; part < 2; ++part) {
    const uint16_t* h = part ? h1 : h0;
    const float* wb = dec_w + part * 1024 + (size_t)l * 16;
    float hv[16];
    const bf16x8* hp = (const bf16x8*)(h + l * 16);
    bf16x8 v0 = hp[0];
    bf16x8 v1 = hp[1];
#pragma unroll
    for (int jj = 0; jj < 8; ++jj) {
      hv[jj] = bf2f((uint16_t)v0[jj]);
      hv[8 + jj] = bf2f((uint16_t)v1[jj]);
    }
#pragma unroll
    for (int c = 0; c < 13; ++c) {
      const float* wc = wb + (size_t)c * 2048;
      float s = 0.0f;
#pragma unroll
      for (int jj = 0; jj < 16; ++jj) s += hv[jj] * wc[jj];
      acc[c] += s;
    }
  }
#pragma unroll
  for (int c = 0; c < 13; ++c) {
    float v = acc[c];
#pragma unroll
    for (int off = 32; off > 0; off >>= 1) v += __shfl_xor(v, off, 64);
    acc[c] = v;
  }
  if (l == 0) {
    int t = t0 + tl;
    float* orow = out + ((size_t)t * 256 + b) * 13;
#pragma unroll
    for (int c = 0; c < 13; ++c) orow[c] = acc[c] + dec_b[c];
  }
}

// ---------------- host ----------------
extern "C" void kernel_launch(void* const* d_in, const int* in_sizes, int n_in,
                              void* d_out, int out_size, void* d_ws, size_t ws_size,
                              hipStream_t stream) {
  const int* tokens = (const int*)d_in[0];
  const float* casing = (const float*)d_in[1];
  const float* pos = (const float*)d_in[2];
  const float* emb = (const float*)d_in[3];
  const float* wi0 = (const float*)d_in[4];
  const float* bi0 = (const float*)d_in[5];
  const float* wh0 = (const float*)d_in[6];
  const float* bh0 = (const float*)d_in[7];
  const float* wi1 = (const float*)d_in[8];
  const float* bi1 = (const float*)d_in[9];
  const float* wh1 = (const float*)d_in[10];
  const float* bh1 = (const float*)d_in[11];
  const float* dec_w = (const float*)d_in[12];
  const float* dec_b = (const float*)d_in[13];
  const float* h_init = (const float*)d_in[14];
  const float* c_init = (const float*)d_in[15];
  float* out = (float*)d_out;
  (void)in_sizes; (void)n_in; (void)out_size;

  char* ws = (char*)d_ws;
  size_t off = 0;
  auto alloc = [&](size_t bytes) {
    char* p = ws + off;
    off += (bytes + 255) & ~(size_t)255;
    return p;
  };
  // fixed buffers (~69 MB)
  uint16_t* W0c = (uint16_t*)alloc(4096ull * 1344 * 2);
  float* b0 = (float*)alloc(4096 * 4);
  uint16_t* W1c = (uint16_t*)alloc(4096ull * 2048 * 2);
  float* b1 = (float*)alloc(4096 * 4);
  uint16_t* x_bf = (uint16_t*)alloc(65536ull * 320 * 2);
  float* c_st = (float*)alloc(SLOT * 4);
  uint32_t* bar = (uint32_t*)alloc(4096 * 4);

  // chunk size: (CH+1) + CH + CH slots of SLOT*2 bytes; CH >= 2 (slot-ring
  // correctness needs input slot != output slot at tl==0)
  const size_t SB = SLOT * 2;  // 524288, already 256-aligned
  int CH = 0;
  for (int c = 64; c >= 2; c >>= 1) {
    if (off + (size_t)(3 * c + 1) * SB + 4096 <= ws_size) { CH = c; break; }
  }
  if (CH == 0) return;  // ws too small (diagnostic: poisoned output)
  uint16_t* h0buf = (uint16_t*)alloc((size_t)(CH + 1) * SB);  // slot CH = h_init
  uint16_t* c0buf = (uint16_t*)alloc((size_t)CH * SB);
  uint16_t* h1buf = (uint16_t*)alloc((size_t)CH * SB);

  k_prep_w0<<<4096, 256, 0, stream>>>(wi0, bi0, wh0, bh0, W0c, b0);
  k_prep_w1<<<4096, 256, 0, stream>>>(wi1, bi1, wh1, bh1, W1c, b1);
  k_embed<<<16384, 256, 0, stream>>>(tokens, casing, pos, emb, x_bf);
  k_init<<<1024, 256, 0, stream>>>(h_init, c_init, h0buf + (size_t)CH * SLOT,
                                   c_st, bar);

  for (int t0 = 0; t0 < 256; t0 += CH) {
    // input slot for tl==0: h_init slot (CH) at t0==0, else prev chunk's
    // last slot (CH-1), which this chunk overwrites only at tl==CH-1,
    // strictly after its tl==0 read (inter-step barriers order it).
    int in_s0 = (t0 == 0) ? CH : CH - 1;
    k_l0chunk<<<256, 256, 0, stream>>>(x_bf, W0c, b0, h0buf, c0buf, c_st,
                                       bar, t0, CH, in_s0);
    k_l1gemm<<<64 * CH, 256, 0, stream>>>(h0buf, W1c, b1, c0buf, h1buf);
    k_decode<<<CH * 64, 256, 0, stream>>>(h0buf, h1buf, dec_w, dec_b, out, t0);
  }
}

// Round 8
// 6761.768 us; speedup vs baseline: 1.1259x; 1.1259x over previous
//
#include <hip/hip_runtime.h>
#include <stdint.h>

// ---------------------------------------------------------------------------
// AWD-LSTM eval forward.  T=256, B=256, H=1024, FEAT=319 (=300+7+12), C=13.
// Layer1's recurrent carry is ignored by the reference -> only layer0 is
// sequential; layer1+decoder are parallel over rows.
// Round 8: persistent layer0 v3.  R7 counters: 22 us/step, 95% idle ->
// per-iter s_barrier convoy + shallow prefetch against ~900cy h latency.
// Changes (math/epilogue/publish identical to passing R7):
//  - wave-private staging: each wave stages the A-rows/B-cols it reads
//    (4 gload_lds/iter/wave) -> NO barrier in the 42-iter K-loop.
//  - depth-7 continuous ring over the whole chunk (8 bufs, vmcnt(24) const):
//    buf=(tile+2*tl)&7; step tails stage next step's x-tiles (h-tiles are
//    first staged at iter 3, after the inter-step barrier).
//  - inter-step barrier per Mb-group (64 blocks, 2-level 8x8 relaxed atomics)
//    -- the 4 batch-row groups are independent recurrence chains.
// ---------------------------------------------------------------------------

typedef __attribute__((ext_vector_type(8))) short bf16x8;
typedef __attribute__((ext_vector_type(4))) float f32x4;

#define SLOT 262144ull  // 256*1024 elements per (B,H) slab

__device__ __forceinline__ uint16_t f2bf(float f) {
  uint32_t u = __float_as_uint(f);
  u += 0x7fffu + ((u >> 16) & 1u);
  return (uint16_t)(u >> 16);
}
__device__ __forceinline__ float bf2f(uint16_t h) {
  return __uint_as_float(((uint32_t)h) << 16);
}
__device__ __forceinline__ float sigmoidf_(float x) {
  return __builtin_amdgcn_rcpf(1.0f + __expf(-x));
}
__device__ __forceinline__ float tanhf_(float x) {
  return 1.0f - 2.0f * __builtin_amdgcn_rcpf(__expf(2.0f * x) + 1.0f);
}
__device__ __forceinline__ void gload_lds16(const void* g, void* l) {
  __builtin_amdgcn_global_load_lds(
      (const __attribute__((address_space(1))) void*)g,
      (__attribute__((address_space(3))) void*)l, 16, 0, 0);
}
// LDS tile: row-major [rows][32 k] bf16; four 16B chunks of each row stored
// permuted: chunk_pos = chunk ^ ((row>>1)&3)  -> ~2-way banks
__device__ __forceinline__ bf16x8 lds_frag(const uint16_t* base, int row, int kc) {
  const uint16_t* p = base + row * 32 + ((kc ^ ((row >> 1) & 3)) << 3);
  return *(const bf16x8*)p;
}
__device__ __forceinline__ f32x4 mfma16(bf16x8 a, bf16x8 b, f32x4 c) {
  return __builtin_amdgcn_mfma_f32_16x16x32_bf16(a, b, c, 0, 0, 0);
}

// ---------------- weight prep ----------------
__global__ __launch_bounds__(256) void k_prep_w0(
    const float* __restrict__ wi0, const float* __restrict__ bi0,
    const float* __restrict__ wh0, const float* __restrict__ bh0,
    uint16_t* __restrict__ W0c, float* __restrict__ b0) {
  int r = blockIdx.x;            // interleaved output row: unit j, gate p
  int p = r & 3, j = r >> 2;
  int src = p * 1024 + j;
  const float* wi = wi0 + (size_t)src * 319;
  const float* wh = wh0 + (size_t)src * 1024;
  uint16_t* dst = W0c + (size_t)r * 1344;
  for (int k = threadIdx.x; k < 1344; k += 256) {
    float v;
    if (k < 319) v = wi[k];
    else if (k == 319) v = 0.0f;
    else v = wh[k - 320];
    dst[k] = f2bf(v);
  }
  if (threadIdx.x == 0) b0[r] = bi0[src] + bh0[src];
}

__global__ __launch_bounds__(256) void k_prep_w1(
    const float* __restrict__ wi1, const float* __restrict__ bi1,
    const float* __restrict__ wh1, const float* __restrict__ bh1,
    uint16_t* __restrict__ W1c, float* __restrict__ b1) {
  int r = blockIdx.x;
  int p = r & 3, j = r >> 2;
  int src = p * 1024 + j;
  const float* wi = wi1 + (size_t)src * 1024;
  const float* wh = wh1 + (size_t)src * 1024;
  uint16_t* dst = W1c + (size_t)r * 2048;
  for (int k = threadIdx.x; k < 2048; k += 256) {
    float v = (k < 1024) ? wi[k] : wh[k - 1024];
    dst[k] = f2bf(v);
  }
  if (threadIdx.x == 0) b1[r] = bi1[src] + bh1[src];
}

__global__ __launch_bounds__(256) void k_init(
    const float* __restrict__ h_init, const float* __restrict__ c_init,
    uint16_t* __restrict__ h_slot, float* __restrict__ c_state,
    uint32_t* __restrict__ bar) {
  int i = blockIdx.x * 256 + threadIdx.x;  // 262144 = 256*1024
  h_slot[i] = f2bf(h_init[i]);             // layer0 slice of h_init
  c_state[i] = c_init[i];
  if (i < 16384) bar[i] = 0;               // 256 steps x 4 groups x 16 u32
}

// ---------------- embedding + concat -> x_bf ----------------
__global__ __launch_bounds__(256) void k_embed(
    const int* __restrict__ tokens, const float* __restrict__ casing,
    const float* __restrict__ pos, const float* __restrict__ emb,
    uint16_t* __restrict__ x_bf) {
  int row = blockIdx.x * 4 + (threadIdx.x >> 6);  // (t*256+b)
  int l = threadIdx.x & 63;
  int tok = tokens[row];
  const float* er = emb + (size_t)tok * 300;
  uint16_t* xr = x_bf + (size_t)row * 320;
#pragma unroll
  for (int c0 = 0; c0 < 320; c0 += 64) {
    int c = c0 + l;
    float v;
    if (c < 300) v = er[c];
    else if (c < 307) v = casing[(size_t)row * 7 + (c - 300)];
    else if (c < 319) v = pos[(size_t)row * 12 + (c - 307)];
    else v = 0.0f;
    xr[c] = f2bf(v);
  }
}

// ---------------- persistent layer0 chunk (CH steps, 1 launch) ----------------
// 256 blocks (1/CU, all resident).  Block = (Mb batch-tile 64, Nb col-tile 64),
// XCD-chunked swizzle.  Each wave (wr,wc) computes A[wr*32..+32] x B[wc*32..+32]
// with wave-private LDS ring (8 bufs x 4 KB) -- no intra-loop barriers.
__global__ __launch_bounds__(256) void k_l0chunk(
    const uint16_t* __restrict__ x_bf, const uint16_t* __restrict__ W0c,
    const float* __restrict__ b0, uint16_t* __restrict__ h0buf,
    uint16_t* __restrict__ c0buf, float* __restrict__ c_st,
    uint32_t* __restrict__ bar, int t0, int CH, int in_s0) {
  __shared__ __align__(16) uint16_t AsAll[4][8][1024];  // wave, buf, 32rx32k
  __shared__ __align__(16) uint16_t BsAll[4][8][1024];
  __shared__ __align__(16) float epi[4][16][40];
  const int tid = threadIdx.x;
  const int w = tid >> 6, l = tid & 63;
  const int wr = w >> 1, wc = w & 1;
  const int lid = (blockIdx.x & 7) * 32 + (blockIdx.x >> 3);  // bijective
  const int Mb = (lid & 3) * 64;    // batch tile
  const int Nb = (lid >> 2) * 64;   // col tile (gate-interleaved)

  // staging geometry: lane -> row l>>2 (+16 for sub 1), LDS slot l&3,
  // global chunk sc = slot ^ ((row>>1)&3)
  const int sc = (l & 3) ^ ((l >> 3) & 3);
  const int ar0 = Mb + wr * 32 + (l >> 2);   // this wave's A rows (sub 0)
  const int br0 = Nb + wc * 32 + (l >> 2);   // this wave's B rows (sub 0)
  const uint16_t* pw0 = W0c + (size_t)br0 * 1344 + sc * 8;
  const uint16_t* pw1 = pw0 + 16 * 1344;
  uint16_t* myA = &AsAll[w][0][0];
  uint16_t* myB = &BsAll[w][0][0];

  auto stage = [&](int j, int bb2, const uint16_t* x0, const uint16_t* x1,
                   const uint16_t* h0, const uint16_t* h1) {
    int buf = (j + bb2) & 7;
    int kg = j * 32;
    const uint16_t* s0 = (j < 10) ? (x0 + kg) : (h0 + (kg - 320));
    const uint16_t* s1 = (j < 10) ? (x1 + kg) : (h1 + (kg - 320));
    gload_lds16(s0, myA + buf * 1024);
    gload_lds16(s1, myA + buf * 1024 + 512);
    gload_lds16(pw0 + kg, myB + buf * 1024);
    gload_lds16(pw1 + kg, myB + buf * 1024 + 512);
  };

  // per-thread cell state: 4 fixed (bg, jg) cells across all steps
  const int jbase = (Nb + wc * 32) >> 2;
  float creg[4];
  int gidx4[4];
#pragma unroll
  for (int m = 0; m < 2; ++m)
#pragma unroll
    for (int it = 0; it < 2; ++it) {
      int pp = it * 64 + l;
      int bg = Mb + wr * 32 + m * 16 + (pp >> 3);
      int jg = jbase + (pp & 7);
      int ci = m * 2 + it;
      gidx4[ci] = bg * 1024 + jg;
      creg[ci] = c_st[gidx4[ci]];
    }

  // prologue: stage tiles 0..6 of step t0 (x-part only)
  {
    const uint16_t* px0 = x_bf + ((size_t)t0 * 256 + ar0) * 320 + sc * 8;
    const uint16_t* px1 = px0 + 16 * 320;
    for (int j = 0; j < 7; ++j) stage(j, 0, px0, px1, px0, px1);
  }

  for (int tl = 0; tl < CH; ++tl) {
    const int t = t0 + tl;
    const int bb = (tl * 2) & 7;           // ring phase (42 mod 8 = 2)
    const int is = (tl > 0) ? (tl - 1) : in_s0;
    const uint16_t* px0 = x_bf + ((size_t)t * 256 + ar0) * 320 + sc * 8;
    const uint16_t* px1 = px0 + 16 * 320;
    const uint16_t* ph0 =
        h0buf + (size_t)is * SLOT + (size_t)ar0 * 1024 + sc * 8;
    const uint16_t* ph1 = ph0 + 16 * 1024;
    const int tn = (tl + 1 < CH) ? (t + 1) : t;  // dummy refetch on last step
    const uint16_t* nx0 = x_bf + ((size_t)tn * 256 + ar0) * 320 + sc * 8;
    const uint16_t* nx1 = nx0 + 16 * 320;

    f32x4 acc[2][2] = {};
    for (int kt = 0; kt < 42; ++kt) {
      asm volatile("s_waitcnt vmcnt(24)" ::: "memory");
      __builtin_amdgcn_sched_barrier(0);
      const uint16_t* Ab = myA + ((kt + bb) & 7) * 1024;
      const uint16_t* Bb = myB + ((kt + bb) & 7) * 1024;
      bf16x8 a0 = lds_frag(Ab, l & 15, l >> 4);
      bf16x8 a1 = lds_frag(Ab, 16 + (l & 15), l >> 4);
      bf16x8 q0 = lds_frag(Bb, l & 15, l >> 4);
      bf16x8 q1 = lds_frag(Bb, 16 + (l & 15), l >> 4);
      int j2 = kt + 7;
      if (j2 <= 41) stage(j2, bb, px0, px1, ph0, ph1);
      else stage(j2 - 42, bb + 2, nx0, nx1, nx0, nx1);  // next-step x tiles
      acc[0][0] = mfma16(a0, q0, acc[0][0]);
      acc[0][1] = mfma16(a0, q1, acc[0][1]);
      acc[1][0] = mfma16(a1, q0, acc[1][0]);
      acc[1][1] = mfma16(a1, q1, acc[1][1]);
    }

    // fused cell epilogue; h -> fresh slot tl via agent atomic u32 (pairs)
    uint32_t* hc = (uint32_t*)(h0buf + (size_t)tl * SLOT);
    uint32_t* cc = (uint32_t*)(c0buf + (size_t)tl * SLOT);
#pragma unroll
    for (int m = 0; m < 2; ++m) {
#pragma unroll
      for (int n = 0; n < 2; ++n)
#pragma unroll
        for (int r = 0; r < 4; ++r)
          epi[w][(l >> 4) * 4 + r][n * 16 + (l & 15)] = acc[m][n][r];
      asm volatile("s_waitcnt lgkmcnt(0)" ::: "memory");
#pragma unroll
      for (int it = 0; it < 2; ++it) {
        int pp = it * 64 + l;
        int rr = pp >> 3, j = pp & 7;
        f32x4 q = *(const f32x4*)&epi[w][rr][j * 4];
        f32x4 bv = *(const f32x4*)&b0[(jbase + j) * 4];
        float vi = sigmoidf_(q[0] + bv[0]);
        float vf = sigmoidf_(q[1] + bv[1]);
        float vo = sigmoidf_(q[2] + bv[2]);
        float vg = tanhf_(q[3] + bv[3]);
        int ci = m * 2 + it;
        float cn = vf * creg[ci] + vi * vg;
        creg[ci] = cn;
        float hh = vo * tanhf_(cn);
        uint32_t hu = f2bf(hh), cu = f2bf(cn);
        uint32_t hp = hu | ((uint32_t)__shfl_xor((int)hu, 1) << 16);
        uint32_t cp = cu | ((uint32_t)__shfl_xor((int)cu, 1) << 16);
        if ((l & 1) == 0) {
          size_t pidx = (size_t)(gidx4[ci] >> 1);
          __hip_atomic_store(hc + pidx, hp, __ATOMIC_RELAXED,
                             __HIP_MEMORY_SCOPE_AGENT);
          cc[pidx] = cp;
        }
      }
      asm volatile("s_waitcnt lgkmcnt(0)" ::: "memory");
    }

    // inter-step barrier, per Mb-group (64 blocks: 8 XCD-groups of 8).
    // __syncthreads drains vmcnt -> all h-stores visible before arrive.
    if (tl + 1 < CH) {
      __syncthreads();
      if (tid == 0) {
        uint32_t* bs = bar + ((size_t)t * 4 + (lid & 3)) * 16;
        uint32_t old = __hip_atomic_fetch_add(
            &bs[blockIdx.x & 7], 1u, __ATOMIC_RELAXED,
            __HIP_MEMORY_SCOPE_AGENT);
        if (old == 7u)
          __hip_atomic_fetch_add(&bs[8], 1u, __ATOMIC_RELAXED,
                                 __HIP_MEMORY_SCOPE_AGENT);
        int spins = 0;
        while (__hip_atomic_load(&bs[8], __ATOMIC_RELAXED,
                                 __HIP_MEMORY_SCOPE_AGENT) < 8u) {
          __builtin_amdgcn_s_sleep(1);
          if (++spins > 2000000) break;  // bounded: bug -> wrong, not hung
        }
      }
      __syncthreads();
      __builtin_amdgcn_sched_barrier(0);
    }
  }
#pragma unroll
  for (int ci = 0; ci < 4; ++ci) c_st[gidx4[ci]] = creg[ci];
}

// ---------------- layer1 GEMM over one chunk ----------------
// rows = CH*256; A row (t,b) = [h0(t,b) | h0(t,255-b)]  (slot tl of h0buf).
// tile 128x128, 4 waves (2x2) x (4x4 frags), fused cell epilogue.
// 1-D grid 64*CH, XCD-chunked swizzle: XCD k owns N-panels [4k,4k+4).
__global__ __launch_bounds__(256) void k_l1gemm(
    const uint16_t* __restrict__ h0buf, const uint16_t* __restrict__ W1c,
    const float* __restrict__ b1, const uint16_t* __restrict__ c0buf,
    uint16_t* __restrict__ h1buf) {
  __shared__ __align__(16) uint16_t As[128 * 32];
  __shared__ __align__(16) uint16_t Bs[128 * 32];
  __shared__ __align__(16) float epi[4][16][68];
  int tid = threadIdx.x;
  int w = tid >> 6, l = tid & 63;
  int wr = w >> 1, wc = w & 1;
  uint32_t G = gridDim.x;          // 64*CH (divisible by 8)
  uint32_t cpx = G >> 3;
  uint32_t lid = (blockIdx.x & 7) * cpx + (blockIdx.x >> 3);  // bijective
  uint32_t yyTot = G >> 5;         // 2*CH row-tiles per N-panel
  uint32_t nb = lid / yyTot;       // N-panel 0..31
  uint32_t yy = lid - nb * yyTot;  // row tile 0..2CH-1
  int Nb = (int)nb * 128;
  int tl = (int)(yy >> 1);
  int bbase = (int)(yy & 1) * 128;
  const uint16_t* hrow = h0buf + (size_t)tl * SLOT;
  const uint16_t* c0s = c0buf + (size_t)tl * SLOT;
  uint16_t* h1s = h1buf + (size_t)tl * SLOT;
  f32x4 acc[4][4] = {};

  int sc = (l & 3) ^ ((l >> 3) & 3);
  int srow0 = (w * 2 + 0) * 16 + (l >> 2);
  int srow1 = (w * 2 + 1) * 16 + (l >> 2);
  const uint16_t* hA0n = hrow + (size_t)(bbase + srow0) * 1024;
  const uint16_t* hA0f = hrow + (size_t)(255 - (bbase + srow0)) * 1024;
  const uint16_t* hA1n = hrow + (size_t)(bbase + srow1) * 1024;
  const uint16_t* hA1f = hrow + (size_t)(255 - (bbase + srow1)) * 1024;
  const uint16_t* wB0 = W1c + (size_t)(Nb + srow0) * 2048;
  const uint16_t* wB1 = W1c + (size_t)(Nb + srow1) * 2048;
  uint16_t* AsW0 = As + (w * 2 + 0) * 512;
  uint16_t* AsW1 = As + (w * 2 + 1) * 512;
  uint16_t* BsW0 = Bs + (w * 2 + 0) * 512;
  uint16_t* BsW1 = Bs + (w * 2 + 1) * 512;

  for (int kt = 0; kt < 64; ++kt) {
    int kg = kt * 32 + sc * 8;
    const uint16_t* sA0 = (kg < 1024) ? (hA0n + kg) : (hA0f + (kg - 1024));
    const uint16_t* sA1 = (kg < 1024) ? (hA1n + kg) : (hA1f + (kg - 1024));
    gload_lds16(sA0, AsW0);
    gload_lds16(sA1, AsW1);
    gload_lds16(wB0 + kg, BsW0);
    gload_lds16(wB1 + kg, BsW1);
    __syncthreads();
    bf16x8 a[4], q[4];
#pragma unroll
    for (int m = 0; m < 4; ++m) a[m] = lds_frag(As, wr * 64 + m * 16 + (l & 15), l >> 4);
#pragma unroll
    for (int n = 0; n < 4; ++n) q[n] = lds_frag(Bs, wc * 64 + n * 16 + (l & 15), l >> 4);
#pragma unroll
    for (int m = 0; m < 4; ++m)
#pragma unroll
      for (int n = 0; n < 4; ++n) acc[m][n] = mfma16(a[m], q[n], acc[m][n]);
    __syncthreads();
  }

  int jbase = (Nb + wc * 64) >> 2;
#pragma unroll
  for (int m = 0; m < 4; ++m) {
#pragma unroll
    for (int n = 0; n < 4; ++n)
#pragma unroll
      for (int r = 0; r < 4; ++r)
        epi[w][(l >> 4) * 4 + r][n * 16 + (l & 15)] = acc[m][n][r];
    asm volatile("s_waitcnt lgkmcnt(0)" ::: "memory");
#pragma unroll
    for (int it = 0; it < 4; ++it) {
      int pp = it * 64 + l;
      int rr = pp >> 4, j = pp & 15;
      f32x4 q = *(const f32x4*)&epi[w][rr][j * 4];
      f32x4 bv = *(const f32x4*)&b1[(size_t)(jbase + j) * 4];
      float vi = sigmoidf_(q[0] + bv[0]);
      float vf = sigmoidf_(q[1] + bv[1]);
      float vo = sigmoidf_(q[2] + bv[2]);
      float vg = tanhf_(q[3] + bv[3]);
      int rowl = wr * 64 + m * 16 + rr;
      int b = bbase + rowl;
      int jg = jbase + j;
      float c0v = bf2f(c0s[(size_t)(255 - b) * 1024 + jg]);
      float cn = vf * c0v + vi * vg;
      float hh = vo * tanhf_(cn);
      h1s[(size_t)b * 1024 + jg] = f2bf(hh);
    }
    asm volatile("s_waitcnt lgkmcnt(0)" ::: "memory");
  }
}

// ---------------- decoder over one chunk ----------------
__global__ __launch_bounds__(256) void k_decode(
    const uint16_t* __restrict__ h0buf, const uint16_t* __restrict__ h1buf,
    const float* __restrict__ dec_w, const float* __restrict__ dec_b,
    float* __restrict__ out, int t0) {
  int rowl = blockIdx.x * 4 + (threadIdx.x >> 6);  // chunk-local row
  int l = threadIdx.x & 63;
  int tl = rowl >> 8, b = rowl & 255;
  const uint16_t* h0 = h0buf + (size_t)tl * SLOT + (size_t)b * 1024;
  const uint16_t* h1 = h1buf + (size_t)tl * SLOT + (size_t)b * 1024;
  float acc[13];
#pragma unroll
  for (int c = 0; c < 13; ++c) acc[c] = 0.0f;
#pragma unroll
  for (int part = 0; part < 2; ++part) {
    const uint16_t* h = part ? h1 : h0;
    const float* wb = dec_w + part * 1024 + (size_t)l * 16;
    float hv[16];
    const bf16x8* hp = (const bf16x8*)(h + l * 16);
    bf16x8 v0 = hp[0];
    bf16x8 v1 = hp[1];
#pragma unroll
    for (int jj = 0; jj < 8; ++jj) {
      hv[jj] = bf2f((uint16_t)v0[jj]);
      hv[8 + jj] = bf2f((uint16_t)v1[jj]);
    }
#pragma unroll
    for (int c = 0; c < 13; ++c) {
      const float* wc = wb + (size_t)c * 2048;
      float s = 0.0f;
#pragma unroll
      for (int jj = 0; jj < 16; ++jj) s += hv[jj] * wc[jj];
      acc[c] += s;
    }
  }
#pragma unroll
  for (int c = 0; c < 13; ++c) {
    float v = acc[c];
#pragma unroll
    for (int off = 32; off > 0; off >>= 1) v += __shfl_xor(v, off, 64);
    acc[c] = v;
  }
  if (l == 0) {
    int t = t0 + tl;
    float* orow = out + ((size_t)t * 256 + b) * 13;
#pragma unroll
    for (int c = 0; c < 13; ++c) orow[c] = acc[c] + dec_b[c];
  }
}

// ---------------- host ----------------
extern "C" void kernel_launch(void* const* d_in, const int* in_sizes, int n_in,
                              void* d_out, int out_size, void* d_ws, size_t ws_size,
                              hipStream_t stream) {
  const int* tokens = (const int*)d_in[0];
  const float* casing = (const float*)d_in[1];
  const float* pos = (const float*)d_in[2];
  const float* emb = (const float*)d_in[3];
  const float* wi0 = (const float*)d_in[4];
  const float* bi0 = (const float*)d_in[5];
  const float* wh0 = (const float*)d_in[6];
  const float* bh0 = (const float*)d_in[7];
  const float* wi1 = (const float*)d_in[8];
  const float* bi1 = (const float*)d_in[9];
  const float* wh1 = (const float*)d_in[10];
  const float* bh1 = (const float*)d_in[11];
  const float* dec_w = (const float*)d_in[12];
  const float* dec_b = (const float*)d_in[13];
  const float* h_init = (const float*)d_in[14];
  const float* c_init = (const float*)d_in[15];
  float* out = (float*)d_out;
  (void)in_sizes; (void)n_in; (void)out_size;

  char* ws = (char*)d_ws;
  size_t off = 0;
  auto alloc = [&](size_t bytes) {
    char* p = ws + off;
    off += (bytes + 255) & ~(size_t)255;
    return p;
  };
  // fixed buffers (~69 MB)
  uint16_t* W0c = (uint16_t*)alloc(4096ull * 1344 * 2);
  float* b0 = (float*)alloc(4096 * 4);
  uint16_t* W1c = (uint16_t*)alloc(4096ull * 2048 * 2);
  float* b1 = (float*)alloc(4096 * 4);
  uint16_t* x_bf = (uint16_t*)alloc(65536ull * 320 * 2);
  float* c_st = (float*)alloc(SLOT * 4);
  uint32_t* bar = (uint32_t*)alloc(16384 * 4);

  // chunk size: (CH+1) + CH + CH slots of SLOT*2 bytes; CH >= 2
  const size_t SB = SLOT * 2;  // 524288, already 256-aligned
  int CH = 0;
  for (int c = 64; c >= 2; c >>= 1) {
    if (off + (size_t)(3 * c + 1) * SB + 4096 <= ws_size) { CH = c; break; }
  }
  if (CH == 0) return;  // ws too small (diagnostic: poisoned output)
  uint16_t* h0buf = (uint16_t*)alloc((size_t)(CH + 1) * SB);  // slot CH = h_init
  uint16_t* c0buf = (uint16_t*)alloc((size_t)CH * SB);
  uint16_t* h1buf = (uint16_t*)alloc((size_t)CH * SB);

  k_prep_w0<<<4096, 256, 0, stream>>>(wi0, bi0, wh0, bh0, W0c, b0);
  k_prep_w1<<<4096, 256, 0, stream>>>(wi1, bi1, wh1, bh1, W1c, b1);
  k_embed<<<16384, 256, 0, stream>>>(tokens, casing, pos, emb, x_bf);
  k_init<<<1024, 256, 0, stream>>>(h_init, c_init, h0buf + (size_t)CH * SLOT,
                                   c_st, bar);

  for (int t0 = 0; t0 < 256; t0 += CH) {
    // input slot for tl==0: h_init slot (CH) at t0==0, else prev chunk's
    // last slot (CH-1), read at tl==0 strictly before its tl==CH-1 rewrite.
    int in_s0 = (t0 == 0) ? CH : CH - 1;
    k_l0chunk<<<256, 256, 0, stream>>>(x_bf, W0c, b0, h0buf, c0buf, c_st,
                                       bar, t0, CH, in_s0);
    k_l1gemm<<<64 * CH, 256, 0, stream>>>(h0buf, W1c, b1, c0buf, h1buf);
    k_decode<<<CH * 64, 256, 0, stream>>>(h0buf, h1buf, dec_w, dec_b, out, t0);
  }
}

// Round 9
// 6311.716 us; speedup vs baseline: 1.2062x; 1.0713x over previous
//
#include <hip/hip_runtime.h>
#include <stdint.h>

// ---------------------------------------------------------------------------
// AWD-LSTM eval forward.  T=256, B=256, H=1024, FEAT=319 (=300+7+12), C=13.
// Layer1's recurrent carry is ignored by the reference -> only layer0 is
// sequential; layer1+decoder are parallel over rows.
// Round 9: occupancy attack.  All prior rounds ran layer0 at 1 wave/SIMD
// (Occupancy 12.3%); step time was ~19 us invariant across launch/persistent/
// pipeline variants -> waits can't be hidden with nothing co-resident.
// k_step now: tile 64Mx32N, grid 512 = 2 blocks/CU (2 waves/SIMD), 4 waves
// 2x2 over (32M,16N); R6-proven 4-buffer vmcnt(4) staging, per-wave-uniform
// 2 loads/iter (B halves duplicated by wave pairs -- benign identical race).
// GEMMs: bf16 MFMA 16x16x32, f32 accum; weights gate-interleaved
// (col 4j+p = gate p of unit j) so the LSTM cell fuses into the epilogue.
// ---------------------------------------------------------------------------

typedef __attribute__((ext_vector_type(8))) short bf16x8;
typedef __attribute__((ext_vector_type(4))) float f32x4;

#define SLOT 262144ull  // 256*1024 elements per (B,H) slab

__device__ __forceinline__ uint16_t f2bf(float f) {
  uint32_t u = __float_as_uint(f);
  u += 0x7fffu + ((u >> 16) & 1u);
  return (uint16_t)(u >> 16);
}
__device__ __forceinline__ float bf2f(uint16_t h) {
  return __uint_as_float(((uint32_t)h) << 16);
}
__device__ __forceinline__ float sigmoidf_(float x) {
  return __builtin_amdgcn_rcpf(1.0f + __expf(-x));
}
__device__ __forceinline__ float tanhf_(float x) {
  return 1.0f - 2.0f * __builtin_amdgcn_rcpf(__expf(2.0f * x) + 1.0f);
}
__device__ __forceinline__ void gload_lds16(const void* g, void* l) {
  __builtin_amdgcn_global_load_lds(
      (const __attribute__((address_space(1))) void*)g,
      (__attribute__((address_space(3))) void*)l, 16, 0, 0);
}
// LDS tile: row-major [rows][32 k] bf16; four 16B chunks of each row stored
// permuted: chunk_pos = chunk ^ ((row>>1)&3)  -> ~2-way banks
__device__ __forceinline__ bf16x8 lds_frag(const uint16_t* base, int row, int kc) {
  const uint16_t* p = base + row * 32 + ((kc ^ ((row >> 1) & 3)) << 3);
  return *(const bf16x8*)p;
}
__device__ __forceinline__ f32x4 mfma16(bf16x8 a, bf16x8 b, f32x4 c) {
  return __builtin_amdgcn_mfma_f32_16x16x32_bf16(a, b, c, 0, 0, 0);
}

// ---------------- weight prep ----------------
__global__ __launch_bounds__(256) void k_prep_w0(
    const float* __restrict__ wi0, const float* __restrict__ bi0,
    const float* __restrict__ wh0, const float* __restrict__ bh0,
    uint16_t* __restrict__ W0c, float* __restrict__ b0) {
  int r = blockIdx.x;            // interleaved output row: unit j, gate p
  int p = r & 3, j = r >> 2;
  int src = p * 1024 + j;
  const float* wi = wi0 + (size_t)src * 319;
  const float* wh = wh0 + (size_t)src * 1024;
  uint16_t* dst = W0c + (size_t)r * 1344;
  for (int k = threadIdx.x; k < 1344; k += 256) {
    float v;
    if (k < 319) v = wi[k];
    else if (k == 319) v = 0.0f;
    else v = wh[k - 320];
    dst[k] = f2bf(v);
  }
  if (threadIdx.x == 0) b0[r] = bi0[src] + bh0[src];
}

__global__ __launch_bounds__(256) void k_prep_w1(
    const float* __restrict__ wi1, const float* __restrict__ bi1,
    const float* __restrict__ wh1, const float* __restrict__ bh1,
    uint16_t* __restrict__ W1c, float* __restrict__ b1) {
  int r = blockIdx.x;
  int p = r & 3, j = r >> 2;
  int src = p * 1024 + j;
  const float* wi = wi1 + (size_t)src * 1024;
  const float* wh = wh1 + (size_t)src * 1024;
  uint16_t* dst = W1c + (size_t)r * 2048;
  for (int k = threadIdx.x; k < 2048; k += 256) {
    float v = (k < 1024) ? wi[k] : wh[k - 1024];
    dst[k] = f2bf(v);
  }
  if (threadIdx.x == 0) b1[r] = bi1[src] + bh1[src];
}

__global__ __launch_bounds__(256) void k_init(
    const float* __restrict__ h_init, const float* __restrict__ c_init,
    uint16_t* __restrict__ h_slot, float* __restrict__ c_state) {
  int i = blockIdx.x * 256 + threadIdx.x;  // 262144 = 256*1024
  h_slot[i] = f2bf(h_init[i]);             // layer0 slice of h_init
  c_state[i] = c_init[i];
}

// ---------------- embedding + concat -> x_bf ----------------
__global__ __launch_bounds__(256) void k_embed(
    const int* __restrict__ tokens, const float* __restrict__ casing,
    const float* __restrict__ pos, const float* __restrict__ emb,
    uint16_t* __restrict__ x_bf) {
  int row = blockIdx.x * 4 + (threadIdx.x >> 6);  // (t*256+b)
  int l = threadIdx.x & 63;
  int tok = tokens[row];
  const float* er = emb + (size_t)tok * 300;
  uint16_t* xr = x_bf + (size_t)row * 320;
#pragma unroll
  for (int c0 = 0; c0 < 320; c0 += 64) {
    int c = c0 + l;
    float v;
    if (c < 300) v = er[c];
    else if (c < 307) v = casing[(size_t)row * 7 + (c - 300)];
    else if (c < 319) v = pos[(size_t)row * 12 + (c - 307)];
    else v = 0.0f;
    xr[c] = f2bf(v);
  }
}

// ---------------- layer0 sequential step ----------------
// GEMM [256 x 1344] @ [4096 x 1344]^T, tile 64M x 32N, grid 512 (2 blocks/CU),
// 4 waves 2x2 over (32M,16N).  Staging: 4-buffer ring, vmcnt(4), one barrier
// per iter; wave w stages A rows [16w,16w+16) and B half (w&1) (duplicated by
// wave pairs -> uniform 2 loads/wave/iter).  Fused LSTM-cell epilogue.
// XCD-chunked swizzle: XCD k owns N-panels [16k,16k+16) (1.4 MB W, L2-res).
__global__ __launch_bounds__(256, 2) void k_step(
    const uint16_t* __restrict__ x_t, const uint16_t* __restrict__ W0c,
    const float* __restrict__ b0, const uint16_t* __restrict__ h_in,
    uint16_t* __restrict__ h_out, uint16_t* __restrict__ c0_out,
    float* __restrict__ c_state) {
  __shared__ __align__(16) uint16_t As[4][2048];  // 64 rows x 32 k
  __shared__ __align__(16) uint16_t Bs[4][1024];  // 32 rows x 32 k
  __shared__ __align__(16) float epi[4][16][20];
  int tid = threadIdx.x;
  int w = tid >> 6, l = tid & 63;
  int wr = w >> 1, wc = w & 1;
  int lid = (blockIdx.x & 7) * 64 + (blockIdx.x >> 3);  // bijective (512=8*64)
  int Mb = (lid & 3) * 64;    // batch tile (64 rows)
  int Nb = (lid >> 2) * 32;   // output-col tile (32 interleaved cols)
  f32x4 acc[2] = {};

  // staging: wave w -> A rows 16w..16w+16; B rows 16(w&1)..+16 (dup by pair)
  int sc = (l & 3) ^ ((l >> 3) & 3);  // global chunk for this lane's LDS slot
  const uint16_t* xrow = x_t + (size_t)(Mb + w * 16 + (l >> 2)) * 320 + sc * 8;
  const uint16_t* hrow = h_in + (size_t)(Mb + w * 16 + (l >> 2)) * 1024 + sc * 8;
  const uint16_t* wrow =
      W0c + (size_t)(Nb + (w & 1) * 16 + (l >> 2)) * 1344 + sc * 8;

  auto stage = [&](int kt, int buf) {
    int kg = kt * 32;
    const uint16_t* sA = (kt < 10) ? (xrow + kg) : (hrow + (kg - 320));
    gload_lds16(sA, &As[buf][w * 512]);
    gload_lds16(wrow + kg, &Bs[buf][(w & 1) * 512]);
  };

  stage(0, 0);
  stage(1, 1);
  stage(2, 2);
  for (int kt = 0; kt < 42; ++kt) {
    __builtin_amdgcn_sched_barrier(0);
    if (kt < 40) asm volatile("s_waitcnt vmcnt(4)" ::: "memory");
    else if (kt == 40) asm volatile("s_waitcnt vmcnt(2)" ::: "memory");
    else asm volatile("s_waitcnt vmcnt(0)" ::: "memory");
    __builtin_amdgcn_s_barrier();
    __builtin_amdgcn_sched_barrier(0);
    if (kt < 39) stage(kt + 3, (kt + 3) & 3);
    const uint16_t* Ab = As[kt & 3];
    const uint16_t* Bb = Bs[kt & 3];
    bf16x8 a0 = lds_frag(Ab, wr * 32 + (l & 15), l >> 4);
    bf16x8 a1 = lds_frag(Ab, wr * 32 + 16 + (l & 15), l >> 4);
    bf16x8 q0 = lds_frag(Bb, wc * 16 + (l & 15), l >> 4);
    acc[0] = mfma16(a0, q0, acc[0]);
    acc[1] = mfma16(a1, q0, acc[1]);
  }

  // fused LSTM cell epilogue: per wave 32x16 outputs = 2 frags, 2 cells/thread
  int jbase = (Nb + wc * 16) >> 2;
#pragma unroll
  for (int m = 0; m < 2; ++m) {
#pragma unroll
    for (int r = 0; r < 4; ++r)
      epi[w][(l >> 4) * 4 + r][l & 15] = acc[m][r];
    asm volatile("s_waitcnt lgkmcnt(0)" ::: "memory");
    {
      int rr = l >> 2, j = l & 3;
      f32x4 q = *(const f32x4*)&epi[w][rr][j * 4];
      f32x4 bv = *(const f32x4*)&b0[(jbase + j) * 4];
      float vi = sigmoidf_(q[0] + bv[0]);
      float vf = sigmoidf_(q[1] + bv[1]);
      float vo = sigmoidf_(q[2] + bv[2]);
      float vg = tanhf_(q[3] + bv[3]);
      int bg = Mb + wr * 32 + m * 16 + rr;
      int jg = jbase + j;
      size_t sidx = (size_t)bg * 1024 + jg;
      float cold = c_state[sidx];
      float cn = vf * cold + vi * vg;
      float hh = vo * tanhf_(cn);
      c_state[sidx] = cn;
      c0_out[sidx] = f2bf(cn);
      h_out[sidx] = f2bf(hh);
    }
    asm volatile("s_waitcnt lgkmcnt(0)" ::: "memory");
  }
}

// ---------------- layer1 GEMM over one chunk ----------------
// rows = CH*256; A row (t,b) = [h0(t,b) | h0(t,255-b)]  (slot tl of h0buf).
// tile 128x128, 4 waves (2x2) x (4x4 frags), fused cell epilogue.
// 1-D grid 64*CH, XCD-chunked swizzle: XCD k owns N-panels [4k,4k+4).
__global__ __launch_bounds__(256) void k_l1gemm(
    const uint16_t* __restrict__ h0buf, const uint16_t* __restrict__ W1c,
    const float* __restrict__ b1, const uint16_t* __restrict__ c0buf,
    uint16_t* __restrict__ h1buf) {
  __shared__ __align__(16) uint16_t As[128 * 32];
  __shared__ __align__(16) uint16_t Bs[128 * 32];
  __shared__ __align__(16) float epi[4][16][68];
  int tid = threadIdx.x;
  int w = tid >> 6, l = tid & 63;
  int wr = w >> 1, wc = w & 1;
  uint32_t G = gridDim.x;          // 64*CH (divisible by 8)
  uint32_t cpx = G >> 3;
  uint32_t lid = (blockIdx.x & 7) * cpx + (blockIdx.x >> 3);  // bijective
  uint32_t yyTot = G >> 5;         // 2*CH row-tiles per N-panel
  uint32_t nb = lid / yyTot;       // N-panel 0..31
  uint32_t yy = lid - nb * yyTot;  // row tile 0..2CH-1
  int Nb = (int)nb * 128;
  int tl = (int)(yy >> 1);
  int bbase = (int)(yy & 1) * 128;
  const uint16_t* hrow = h0buf + (size_t)tl * SLOT;
  const uint16_t* c0s = c0buf + (size_t)tl * SLOT;
  uint16_t* h1s = h1buf + (size_t)tl * SLOT;
  f32x4 acc[4][4] = {};

  int sc = (l & 3) ^ ((l >> 3) & 3);
  int srow0 = (w * 2 + 0) * 16 + (l >> 2);
  int srow1 = (w * 2 + 1) * 16 + (l >> 2);
  const uint16_t* hA0n = hrow + (size_t)(bbase + srow0) * 1024;
  const uint16_t* hA0f = hrow + (size_t)(255 - (bbase + srow0)) * 1024;
  const uint16_t* hA1n = hrow + (size_t)(bbase + srow1) * 1024;
  const uint16_t* hA1f = hrow + (size_t)(255 - (bbase + srow1)) * 1024;
  const uint16_t* wB0 = W1c + (size_t)(Nb + srow0) * 2048;
  const uint16_t* wB1 = W1c + (size_t)(Nb + srow1) * 2048;
  uint16_t* AsW0 = As + (w * 2 + 0) * 512;
  uint16_t* AsW1 = As + (w * 2 + 1) * 512;
  uint16_t* BsW0 = Bs + (w * 2 + 0) * 512;
  uint16_t* BsW1 = Bs + (w * 2 + 1) * 512;

  for (int kt = 0; kt < 64; ++kt) {
    int kg = kt * 32 + sc * 8;
    const uint16_t* sA0 = (kg < 1024) ? (hA0n + kg) : (hA0f + (kg - 1024));
    const uint16_t* sA1 = (kg < 1024) ? (hA1n + kg) : (hA1f + (kg - 1024));
    gload_lds16(sA0, AsW0);
    gload_lds16(sA1, AsW1);
    gload_lds16(wB0 + kg, BsW0);
    gload_lds16(wB1 + kg, BsW1);
    __syncthreads();
    bf16x8 a[4], q[4];
#pragma unroll
    for (int m = 0; m < 4; ++m) a[m] = lds_frag(As, wr * 64 + m * 16 + (l & 15), l >> 4);
#pragma unroll
    for (int n = 0; n < 4; ++n) q[n] = lds_frag(Bs, wc * 64 + n * 16 + (l & 15), l >> 4);
#pragma unroll
    for (int m = 0; m < 4; ++m)
#pragma unroll
      for (int n = 0; n < 4; ++n) acc[m][n] = mfma16(a[m], q[n], acc[m][n]);
    __syncthreads();
  }

  int jbase = (Nb + wc * 64) >> 2;
#pragma unroll
  for (int m = 0; m < 4; ++m) {
#pragma unroll
    for (int n = 0; n < 4; ++n)
#pragma unroll
      for (int r = 0; r < 4; ++r)
        epi[w][(l >> 4) * 4 + r][n * 16 + (l & 15)] = acc[m][n][r];
    asm volatile("s_waitcnt lgkmcnt(0)" ::: "memory");
#pragma unroll
    for (int it = 0; it < 4; ++it) {
      int pp = it * 64 + l;
      int rr = pp >> 4, j = pp & 15;
      f32x4 q = *(const f32x4*)&epi[w][rr][j * 4];
      f32x4 bv = *(const f32x4*)&b1[(size_t)(jbase + j) * 4];
      float vi = sigmoidf_(q[0] + bv[0]);
      float vf = sigmoidf_(q[1] + bv[1]);
      float vo = sigmoidf_(q[2] + bv[2]);
      float vg = tanhf_(q[3] + bv[3]);
      int rowl = wr * 64 + m * 16 + rr;
      int b = bbase + rowl;
      int jg = jbase + j;
      float c0v = bf2f(c0s[(size_t)(255 - b) * 1024 + jg]);
      float cn = vf * c0v + vi * vg;
      float hh = vo * tanhf_(cn);
      h1s[(size_t)b * 1024 + jg] = f2bf(hh);
    }
    asm volatile("s_waitcnt lgkmcnt(0)" ::: "memory");
  }
}

// ---------------- decoder over one chunk ----------------
__global__ __launch_bounds__(256) void k_decode(
    const uint16_t* __restrict__ h0buf, const uint16_t* __restrict__ h1buf,
    const float* __restrict__ dec_w, const float* __restrict__ dec_b,
    float* __restrict__ out, int t0) {
  int rowl = blockIdx.x * 4 + (threadIdx.x >> 6);  // chunk-local row
  int l = threadIdx.x & 63;
  int tl = rowl >> 8, b = rowl & 255;
  const uint16_t* h0 = h0buf + (size_t)tl * SLOT + (size_t)b * 1024;
  const uint16_t* h1 = h1buf + (size_t)tl * SLOT + (size_t)b * 1024;
  float acc[13];
#pragma unroll
  for (int c = 0; c < 13; ++c) acc[c] = 0.0f;
#pragma unroll
  for (int part = 0; part < 2; ++part) {
    const uint16_t* h = part ? h1 : h0;
    const float* wb = dec_w + part * 1024 + (size_t)l * 16;
    float hv[16];
    const bf16x8* hp = (const bf16x8*)(h + l * 16);
    bf16x8 v0 = hp[0];
    bf16x8 v1 = hp[1];
#pragma unroll
    for (int jj = 0; jj < 8; ++jj) {
      hv[jj] = bf2f((uint16_t)v0[jj]);
      hv[8 + jj] = bf2f((uint16_t)v1[jj]);
    }
#pragma unroll
    for (int c = 0; c < 13; ++c) {
      const float* wc = wb + (size_t)c * 2048;
      float s = 0.0f;
#pragma unroll
      for (int jj = 0; jj < 16; ++jj) s += hv[jj] * wc[jj];
      acc[c] += s;
    }
  }
#pragma unroll
  for (int c = 0; c < 13; ++c) {
    float v = acc[c];
#pragma unroll
    for (int off = 32; off > 0; off >>= 1) v += __shfl_xor(v, off, 64);
    acc[c] = v;
  }
  if (l == 0) {
    int t = t0 + tl;
    float* orow = out + ((size_t)t * 256 + b) * 13;
#pragma unroll
    for (int c = 0; c < 13; ++c) orow[c] = acc[c] + dec_b[c];
  }
}

// ---------------- host ----------------
extern "C" void kernel_launch(void* const* d_in, const int* in_sizes, int n_in,
                              void* d_out, int out_size, void* d_ws, size_t ws_size,
                              hipStream_t stream) {
  const int* tokens = (const int*)d_in[0];
  const float* casing = (const float*)d_in[1];
  const float* pos = (const float*)d_in[2];
  const float* emb = (const float*)d_in[3];
  const float* wi0 = (const float*)d_in[4];
  const float* bi0 = (const float*)d_in[5];
  const float* wh0 = (const float*)d_in[6];
  const float* bh0 = (const float*)d_in[7];
  const float* wi1 = (const float*)d_in[8];
  const float* bi1 = (const float*)d_in[9];
  const float* wh1 = (const float*)d_in[10];
  const float* bh1 = (const float*)d_in[11];
  const float* dec_w = (const float*)d_in[12];
  const float* dec_b = (const float*)d_in[13];
  const float* h_init = (const float*)d_in[14];
  const float* c_init = (const float*)d_in[15];
  float* out = (float*)d_out;
  (void)in_sizes; (void)n_in; (void)out_size;

  char* ws = (char*)d_ws;
  size_t off = 0;
  auto alloc = [&](size_t bytes) {
    char* p = ws + off;
    off += (bytes + 255) & ~(size_t)255;
    return p;
  };
  // fixed buffers (~69 MB)
  uint16_t* W0c = (uint16_t*)alloc(4096ull * 1344 * 2);
  float* b0 = (float*)alloc(4096 * 4);
  uint16_t* W1c = (uint16_t*)alloc(4096ull * 2048 * 2);
  float* b1 = (float*)alloc(4096 * 4);
  uint16_t* x_bf = (uint16_t*)alloc(65536ull * 320 * 2);
  float* c_st = (float*)alloc(SLOT * 4);

  // chunk size: (CH+1) + CH + CH slots of SLOT*2 bytes
  const size_t SB = SLOT * 2;  // 524288, 256-aligned
  int CH = 0;
  for (int c = 64; c >= 2; c >>= 1) {
    if (off + (size_t)(3 * c + 1) * SB + 4096 <= ws_size) { CH = c; break; }
  }
  if (CH == 0) return;  // ws too small (diagnostic: poisoned output)
  uint16_t* h0buf = (uint16_t*)alloc((size_t)(CH + 1) * SB);  // slot CH = h_init
  uint16_t* c0buf = (uint16_t*)alloc((size_t)CH * SB);
  uint16_t* h1buf = (uint16_t*)alloc((size_t)CH * SB);

  k_prep_w0<<<4096, 256, 0, stream>>>(wi0, bi0, wh0, bh0, W0c, b0);
  k_prep_w1<<<4096, 256, 0, stream>>>(wi1, bi1, wh1, bh1, W1c, b1);
  k_embed<<<16384, 256, 0, stream>>>(tokens, casing, pos, emb, x_bf);
  k_init<<<1024, 256, 0, stream>>>(h_init, c_init, h0buf + (size_t)CH * SLOT,
                                   c_st);

  for (int t0 = 0; t0 < 256; t0 += CH) {
    for (int tl = 0; tl < CH; ++tl) {
      int t = t0 + tl;
      // input slot: tl-1; first step reads prev chunk's last slot (CH-1),
      // intact until its tl==CH-1 rewrite -- or h_init slot CH at t=0.
      int in_s = (tl > 0) ? (tl - 1) : ((t0 == 0) ? CH : CH - 1);
      k_step<<<512, 256, 0, stream>>>(
          x_bf + (size_t)t * 81920, W0c, b0,
          h0buf + (size_t)in_s * SLOT,
          h0buf + (size_t)tl * SLOT,
          c0buf + (size_t)tl * SLOT, c_st);
    }
    k_l1gemm<<<64 * CH, 256, 0, stream>>>(h0buf, W1c, b1, c0buf, h1buf);
    k_decode<<<CH * 64, 256, 0, stream>>>(h0buf, h1buf, dec_w, dec_b, out, t0);
  }
}